// Round 13
// baseline (187.792 us; speedup 1.0000x reference)
//
#include <hip/hip_runtime.h>

// Fused ConvTranspose3d(32->64,K=5,S=2,P=2)+bias+MaxPool2+MaxPool3+channel-sum.
// Round 13: M4N4 (R7 wave shape: 2 batches x 4 mtiles x 2 cell-tiles) — the only
// shape whose pipe floors are MFMA-led (MFMA 151K > LDS 125K > A-L1 122K cyc/CU) —
// plus a FULLY-STATIC ping-pong tap pipeline to kill the 2-waves/SIMD latency
// exposure that sank R7 (187us at 3x its floor).
//  vs R8/R9 (spilled pipelines): full unroll -> all tap offsets are instruction
//  immediates (ds 16-bit imm, global 13-bit imm); named a0/b0/a1/b1 sets (no
//  copies); sched_barrier(0) per MFMA group stops whole-region load hoisting.
//  - 1000 blocks = 2 batch-groups x 500 spatial; 256 thr / 4 waves / 8 batches
//  - kb-major xs layout [bb][kb][pos]x16B; 8-cin gather + ds_write_b128 staging
//  - XCD-bijective blockIdx swizzle (1000 % 8 == 0)

typedef __attribute__((ext_vector_type(8))) short short8;
typedef __attribute__((ext_vector_type(4))) float f32x4;

#define CIN 32
#define COUT 64

static __device__ __forceinline__ short f2bf(float f) {
  unsigned u = __float_as_uint(f);
  return (short)((u + 0x7fffu + ((u >> 16) & 1u)) >> 16);  // RNE
}

// Wr[tap][mtile][lane][j] = bf16(W[cin=8*(lane>>4)+j][cout=16*mtile+(lane&15)][tap])
__global__ __launch_bounds__(256) void reorder_w(const float* __restrict__ w,
                                                 short* __restrict__ wr) {
  const int t = blockIdx.x * 256 + threadIdx.x;  // 0..31999
  const int l = t & 63, mt = (t >> 6) & 3, tap = t >> 8;
  const int cout = 16 * mt + (l & 15);
  const int kb = l >> 4;
  short8 v;
#pragma unroll
  for (int j = 0; j < 8; ++j)
    v[j] = f2bf(w[((8 * kb + j) * COUT + cout) * 125 + tap]);
  *(short8*)&wr[t * 8] = v;
}

// cell->column tables (pos = cd*25+ch*5+cw), residue-balanced mod 8.
#define E0 (0ULL | 1ULL<<6 | 2ULL<<12 | 27ULL<<18 | 52ULL<<24 | 5ULL<<30 | 6ULL<<36 | 7ULL<<42)
#define E1 (32ULL | 25ULL<<6 | 26ULL<<12 | 51ULL<<18 | 12ULL<<24 | 37ULL<<30 | 30ULL<<36 | 55ULL<<42)
#define O0 (56ULL | 57ULL<<6 | 50ULL<<12 | 11ULL<<18 | 36ULL<<24 | 61ULL<<30 | 62ULL<<36 | 31ULL<<42)
#define O1 (0ULL | 1ULL<<6 | 10ULL<<12 | 35ULL<<18 | 60ULL<<24 | 5ULL<<30 | 6ULL<<36 | 7ULL<<42)

// tap index helpers (constant-folded under full unroll)
static __device__ __forceinline__ int tap_short_off(int t, int PD, int PH, int PW,
                                                    int NTH, int NTW) {
  const int td = t / (NTH * NTW), th = (t / NTW) % NTH, tw = t % NTW;
  return ((PD + 2 * td) * 25 + (PH + 2 * th) * 5 + (PW + 2 * tw)) * 2048;
}
static __device__ __forceinline__ int toff_short(int t, int NTH, int NTW) {
  const int td = t / (NTH * NTW), th = (t / NTW) % NTH, tw = t % NTW;
  return ((2 - td) * 25 + (2 - th) * 5 + (2 - tw)) * 8;
}

template <int PD, int PH, int PW>
static __device__ __forceinline__ void parity_pass(
    const short* __restrict__ wbase, const short* __restrict__ xs,
    const int (&baddr)[4], float (&mreg)[4][2][4]) {
  constexpr int NTD = 3 - PD, NTH = 3 - PH, NTW = 3 - PW;
  constexpr int N = NTD * NTH * NTW;

  f32x4 acc[4][4];  // [mm][i]
#pragma unroll
  for (int mm = 0; mm < 4; ++mm)
#pragma unroll
    for (int i = 0; i < 4; ++i) acc[mm][i] = (f32x4){0.f, 0.f, 0.f, 0.f};

  short8 a0[4], b0[4], a1[4], b1[4];

#pragma unroll
  for (int mm = 0; mm < 4; ++mm)
    a0[mm] = *(const short8*)(wbase + tap_short_off(0, PD, PH, PW, NTH, NTW) + mm * 512);
#pragma unroll
  for (int i = 0; i < 4; ++i)
    b0[i] = *(const short8*)&xs[baddr[i] + toff_short(0, NTH, NTW)];

#pragma unroll
  for (int t = 0; t < N; t += 2) {
    if (t + 1 < N) {
#pragma unroll
      for (int mm = 0; mm < 4; ++mm)
        a1[mm] = *(const short8*)(wbase + tap_short_off(t + 1, PD, PH, PW, NTH, NTW) + mm * 512);
#pragma unroll
      for (int i = 0; i < 4; ++i)
        b1[i] = *(const short8*)&xs[baddr[i] + toff_short(t + 1, NTH, NTW)];
    }
#pragma unroll
    for (int mm = 0; mm < 4; ++mm)
#pragma unroll
      for (int i = 0; i < 4; ++i)
        acc[mm][i] = __builtin_amdgcn_mfma_f32_16x16x32_bf16(a0[mm], b0[i], acc[mm][i], 0, 0, 0);
    __builtin_amdgcn_sched_barrier(0);
    if (t + 2 < N) {
#pragma unroll
      for (int mm = 0; mm < 4; ++mm)
        a0[mm] = *(const short8*)(wbase + tap_short_off(t + 2, PD, PH, PW, NTH, NTW) + mm * 512);
#pragma unroll
      for (int i = 0; i < 4; ++i)
        b0[i] = *(const short8*)&xs[baddr[i] + toff_short(t + 2, NTH, NTW)];
    }
    if (t + 1 < N) {
#pragma unroll
      for (int mm = 0; mm < 4; ++mm)
#pragma unroll
        for (int i = 0; i < 4; ++i)
          acc[mm][i] = __builtin_amdgcn_mfma_f32_16x16x32_bf16(a1[mm], b1[i], acc[mm][i], 0, 0, 0);
      __builtin_amdgcn_sched_barrier(0);
    }
  }

#pragma unroll
  for (int mm = 0; mm < 4; ++mm)
#pragma unroll
    for (int bl = 0; bl < 2; ++bl)
#pragma unroll
      for (int q = 0; q < 4; ++q)
        mreg[mm][bl][q] = fmaxf(mreg[mm][bl][q],
                                fmaxf(acc[mm][2 * bl][q], acc[mm][2 * bl + 1][q]));
}

__global__ __launch_bounds__(256) void convt_mfma_r13(
    const float* __restrict__ x, const short* __restrict__ wr,
    const float* __restrict__ bias, float* __restrict__ out) {
  __shared__ short xs[8 * 4 * 125 * 8];  // 64000 B: [bb][kb][pos] x 8 cins (16B units)
  __shared__ float red[8];

  // XCD-bijective swizzle: 1000 blocks, 8 XCDs, 125 per XCD
  const int orig = blockIdx.x;
  const int bi = (orig & 7) * 125 + (orig >> 3);
  const int bg = bi / 500, r = bi % 500;
  const int od = r / 100, oh = (r / 10) % 10, ow = r % 10;
  const int tid = threadIdx.x;
  const int d0 = 3 * od - 1, h0 = 3 * oh - 1, w0 = 3 * ow - 1;
  const int xoff0 = d0 * 1024 + h0 * 32 + w0;

  // ---- stage x -> bf16 tile, 8-cin gather per thread, ds_write_b128 ----
  for (int e = tid; e < 8 * 4 * 128; e += 256) {  // 16 iters
    const int pos = e & 127;
    if (pos < 125) {
      const int kb = (e >> 7) & 3, bb = e >> 9;
      const int id = pos / 25, rem = pos - 25 * id;
      const int ih = rem / 5, iw = rem - 5 * ih;
      const bool ok = (d0 + id) >= 0 && (h0 + ih) >= 0 && (w0 + iw) >= 0;
      const float* xp =
          x + ((size_t)((bg * 8 + bb) * CIN + kb * 8) << 14) + xoff0 + id * 1024 + ih * 32 + iw;
      short8 v8;
#pragma unroll
      for (int j = 0; j < 8; ++j) v8[j] = f2bf(ok ? xp[j << 14] : 0.f);
      *(short8*)&xs[(bb * 500 + kb * 125 + pos) * 8] = v8;
    }
  }
  __syncthreads();

  const int lane = tid & 63, wv = tid >> 6;  // wv = batch-pair index
  const int kb = lane >> 4, c = lane & 15;

  const int pos_e = (int)((c < 8 ? (E0 >> (6 * c)) : (E1 >> (6 * (c - 8)))) & 63ULL);
  const int pos_o = (int)((c < 8 ? (O0 >> (6 * c)) : (O1 >> (6 * (c - 8)))) & 63ULL);

  int baddr[4];  // short-index base per B-frag, i = bl*2 + ct
#pragma unroll
  for (int i = 0; i < 4; ++i) {
    const int bb = 2 * wv + (i >> 1);
    baddr[i] = (bb * 500 + kb * 125 + ((i & 1) ? pos_o : pos_e)) * 8;
  }

  float mreg[4][2][4];  // [mtile][bl][q]
#pragma unroll
  for (int mm = 0; mm < 4; ++mm)
#pragma unroll
    for (int bl = 0; bl < 2; ++bl)
#pragma unroll
      for (int q = 0; q < 4; ++q) mreg[mm][bl][q] = -__builtin_inff();

  const short* __restrict__ wbase = wr + lane * 8;

  parity_pass<0, 0, 0>(wbase, xs, baddr, mreg);
  parity_pass<0, 0, 1>(wbase, xs, baddr, mreg);
  parity_pass<0, 1, 0>(wbase, xs, baddr, mreg);
  parity_pass<0, 1, 1>(wbase, xs, baddr, mreg);
  parity_pass<1, 0, 0>(wbase, xs, baddr, mreg);
  parity_pass<1, 0, 1>(wbase, xs, baddr, mreg);
  parity_pass<1, 1, 0>(wbase, xs, baddr, mreg);
  parity_pass<1, 1, 1>(wbase, xs, baddr, mreg);

  // ---- epilogue: max over cells (lane bits 0-3), +bias, sum over all 64 couts ----
#pragma unroll
  for (int bl = 0; bl < 2; ++bl) {
    float s = 0.f;
#pragma unroll
    for (int mm = 0; mm < 4; ++mm)
#pragma unroll
      for (int q = 0; q < 4; ++q) {
        float v = mreg[mm][bl][q];
        v = fmaxf(v, __shfl_xor(v, 1));
        v = fmaxf(v, __shfl_xor(v, 2));
        v = fmaxf(v, __shfl_xor(v, 4));
        v = fmaxf(v, __shfl_xor(v, 8));
        s += v + bias[16 * mm + 4 * kb + q];
      }
    s += __shfl_xor(s, 16);  // sum across kb groups (16 distinct couts each)
    s += __shfl_xor(s, 32);
    if (lane == 0) red[2 * wv + bl] = s;
  }
  __syncthreads();
  if (tid < 8) {  // tid = local batch
    out[(bg * 8 + tid) * 500 + r] = red[tid];
  }
}

// ---------------- fallback (used only if ws too small) ----------------
__global__ __launch_bounds__(256) void fused_convt_pool(
    const float* __restrict__ x, const float* __restrict__ w,
    const float* __restrict__ bias, float* __restrict__ out) {
  __shared__ float xsf[CIN * 125];
  __shared__ float ws[COUT * 125];
  __shared__ float red[256];
  const int bi = blockIdx.x;
  const int b = bi / 500;
  const int r = bi % 500;
  const int od = r / 100, oh = (r / 10) % 10, ow = r % 10;
  const int tid = threadIdx.x;
  const int d0 = 3 * od - 1, h0 = 3 * oh - 1, w0 = 3 * ow - 1;
  for (int e = tid; e < CIN * 125; e += 256) {
    const int cin = e / 125, q = e % 125;
    const int id = q / 25, ih = (q / 5) % 5, iw = q % 5;
    const int gd = d0 + id, gh = h0 + ih, gw = w0 + iw;
    float v = 0.f;
    if (gd >= 0 && gh >= 0 && gw >= 0)
      v = x[(((b * CIN + cin) * 16 + gd) * 32 + gh) * 32 + gw];
    xsf[e] = v;
  }
  const int cout = tid >> 2;
  const int vs = tid & 3;
  int cellbase[7];
#pragma unroll
  for (int j = 0; j < 7; ++j) {
    int cell = vs + 4 * j;
    if (cell > 26) cell = 26;
    cellbase[j] = (cell / 9) * 25 + ((cell / 3) % 3) * 5 + cell % 3;
  }
  float acc[7][8];
#pragma unroll
  for (int j = 0; j < 7; ++j)
#pragma unroll
    for (int p = 0; p < 8; ++p) acc[j][p] = 0.f;
  for (int cin = 0; cin < CIN; ++cin) {
    __syncthreads();
    const float* wg = w + cin * (COUT * 125);
    for (int e = tid; e < COUT * 125; e += 256) ws[e] = wg[e];
    __syncthreads();
    const float* xc = xsf + cin * 125;
    const float* wc = ws + cout * 125;
#pragma unroll
    for (int pd = 0; pd < 2; ++pd)
#pragma unroll
      for (int ph = 0; ph < 2; ++ph)
#pragma unroll
        for (int pw = 0; pw < 2; ++pw) {
          const int P = pd * 4 + ph * 2 + pw;
          for (int td = 0; td <= 2 - pd; ++td)
            for (int th = 0; th <= 2 - ph; ++th)
              for (int tw = 0; tw <= 2 - pw; ++tw) {
                const float wv2 =
                    wc[(pd + 2 * td) * 25 + (ph + 2 * th) * 5 + (pw + 2 * tw)];
                const float* xp = xc + (2 - td) * 25 + (2 - th) * 5 + (2 - tw);
#pragma unroll
                for (int j = 0; j < 7; ++j)
                  acc[j][P] = fmaf(wv2, xp[cellbase[j]], acc[j][P]);
              }
        }
  }
  float m = acc[0][0];
#pragma unroll
  for (int j = 0; j < 7; ++j)
#pragma unroll
    for (int p = 0; p < 8; ++p) m = fmaxf(m, acc[j][p]);
  red[tid] = m;
  __syncthreads();
  if (tid < 64) {
    float cm = fmaxf(fmaxf(red[tid * 4 + 0], red[tid * 4 + 1]),
                     fmaxf(red[tid * 4 + 2], red[tid * 4 + 3]));
    cm += bias[tid];
    for (int off = 32; off > 0; off >>= 1) cm += __shfl_down(cm, off);
    if (tid == 0) out[bi] = cm;
  }
}

extern "C" void kernel_launch(void* const* d_in, const int* in_sizes, int n_in,
                              void* d_out, int out_size, void* d_ws, size_t ws_size,
                              hipStream_t stream) {
  const float* x = (const float*)d_in[0];
  const float* wgt = (const float*)d_in[1];
  const float* bias = (const float*)d_in[2];
  float* out = (float*)d_out;
  const size_t wr_bytes = 125 * 4 * 64 * 8 * sizeof(short);  // 512000
  if (ws_size >= wr_bytes) {
    short* wr = (short*)d_ws;
    reorder_w<<<125, 256, 0, stream>>>(wgt, wr);
    convt_mfma_r13<<<1000, 256, 0, stream>>>(x, wr, bias, out);
  } else {
    fused_convt_pool<<<8000, 256, 0, stream>>>(x, wgt, bias, out);
  }
}

// Round 14
// 139.529 us; speedup vs baseline: 1.3459x; 1.3459x over previous
//
#include <hip/hip_runtime.h>

// Fused ConvTranspose3d(32->64,K=5,S=2,P=2)+bias+MaxPool2+MaxPool3+channel-sum.
// Round 14: B-register d-axis reuse on the R11 shape. Per lane the 125 tap B-reads
// hit only 27 distinct LDS addresses (toff = (2-td,2-th,2-tw)). Hold the 3 d-axis
// frags per (th,tw) group in registers; 5 d-taps (both d-parities) consume them ->
// B-LDS traffic 4GB -> 2.4GB; MFMA becomes the max pipe (151K cyc/CU).
//  - wave = 2 mtiles x (2 batches x 2 cell-tiles) [M=2,N=4: A=2GB via L1 bcast]
//  - acc[2][2][4] holds BOTH d-parities during a (PH,PW) pass (64 VGPR)
//  - 2000 blocks = 4 batch-groups x 500 spatial; 256 thr / 4 waves / 4 batches;
//    32KB LDS -> 3 blocks/CU at ~160 VGPR
//  - plain scheduling (R8/R9/R13: hand pipelines lose occupancy), unroll-1 on
//    pass/group loops, static DTAP bodies (compile-time acc/B3 indices)
//  - kb-major xs layout; 8-cin gather + ds_write_b128; XCD swizzle (2000%8==0)

typedef __attribute__((ext_vector_type(8))) short short8;
typedef __attribute__((ext_vector_type(4))) float f32x4;

#define CIN 32
#define COUT 64

static __device__ __forceinline__ short f2bf(float f) {
  unsigned u = __float_as_uint(f);
  return (short)((u + 0x7fffu + ((u >> 16) & 1u)) >> 16);  // RNE
}

// Wr[tap][mtile][lane][j] = bf16(W[cin=8*(lane>>4)+j][cout=16*mtile+(lane&15)][tap])
__global__ __launch_bounds__(256) void reorder_w(const float* __restrict__ w,
                                                 short* __restrict__ wr) {
  const int t = blockIdx.x * 256 + threadIdx.x;  // 0..31999
  const int l = t & 63, mt = (t >> 6) & 3, tap = t >> 8;
  const int cout = 16 * mt + (l & 15);
  const int kb = l >> 4;
  short8 v;
#pragma unroll
  for (int j = 0; j < 8; ++j)
    v[j] = f2bf(w[((8 * kb + j) * COUT + cout) * 125 + tap]);
  *(short8*)&wr[t * 8] = v;
}

// cell->column tables (pos = cd*25+ch*5+cw), residue-balanced mod 8.
#define E0 (0ULL | 1ULL<<6 | 2ULL<<12 | 27ULL<<18 | 52ULL<<24 | 5ULL<<30 | 6ULL<<36 | 7ULL<<42)
#define E1 (32ULL | 25ULL<<6 | 26ULL<<12 | 51ULL<<18 | 12ULL<<24 | 37ULL<<30 | 30ULL<<36 | 55ULL<<42)
#define O0 (56ULL | 57ULL<<6 | 50ULL<<12 | 11ULL<<18 | 36ULL<<24 | 61ULL<<30 | 62ULL<<36 | 31ULL<<42)
#define O1 (0ULL | 1ULL<<6 | 10ULL<<12 | 35ULL<<18 | 60ULL<<24 | 5ULL<<30 | 6ULL<<36 | 7ULL<<42)

__global__ __launch_bounds__(256) void convt_mfma_r14(
    const float* __restrict__ x, const short* __restrict__ wr,
    const float* __restrict__ bias, float* __restrict__ out) {
  __shared__ short xs[4 * 4 * 125 * 8];  // 32000 B: [bb][kb][pos] x 8 cins
  __shared__ float red[8];

  // XCD-bijective swizzle: 2000 blocks, 8 XCDs, 250 per XCD
  const int orig = blockIdx.x;
  const int bi = (orig & 7) * 250 + (orig >> 3);
  const int bg = bi / 500, r = bi % 500;
  const int od = r / 100, oh = (r / 10) % 10, ow = r % 10;
  const int tid = threadIdx.x;
  const int d0 = 3 * od - 1, h0 = 3 * oh - 1, w0 = 3 * ow - 1;
  const int xoff0 = d0 * 1024 + h0 * 32 + w0;

  // ---- stage x -> bf16 tile, 8-cin gather per thread, ds_write_b128 ----
  for (int e = tid; e < 4 * 4 * 128; e += 256) {  // 8 iters
    const int pos = e & 127;
    if (pos < 125) {
      const int kb = (e >> 7) & 3, bb = e >> 9;
      const int id = pos / 25, rem = pos - 25 * id;
      const int ih = rem / 5, iw = rem - 5 * ih;
      const bool ok = (d0 + id) >= 0 && (h0 + ih) >= 0 && (w0 + iw) >= 0;
      const float* xp =
          x + ((size_t)((bg * 4 + bb) * CIN + kb * 8) << 14) + xoff0 + id * 1024 + ih * 32 + iw;
      short8 v8;
#pragma unroll
      for (int j = 0; j < 8; ++j) v8[j] = f2bf(ok ? xp[j << 14] : 0.f);
      *(short8*)&xs[(bb * 500 + kb * 125 + pos) * 8] = v8;
    }
  }
  __syncthreads();

  const int lane = tid & 63, wv = tid >> 6;
  const int mhat = wv >> 1;  // cout half
  const int bp = wv & 1;     // batch pair
  const int kb = lane >> 4, c = lane & 15;

  const int pos_e = (int)((c < 8 ? (E0 >> (6 * c)) : (E1 >> (6 * (c - 8)))) & 63ULL);
  const int pos_o = (int)((c < 8 ? (O0 >> (6 * c)) : (O1 >> (6 * (c - 8)))) & 63ULL);

  int baddr[4];  // short-index base per B-frag, i = bl*2 + ct
#pragma unroll
  for (int i = 0; i < 4; ++i) {
    const int bb = 2 * bp + (i >> 1);
    baddr[i] = (bb * 500 + kb * 125 + ((i & 1) ? pos_o : pos_e)) * 8;
  }

  float mreg[2][2][4];  // [mm][bl][q]
#pragma unroll
  for (int mm = 0; mm < 2; ++mm)
#pragma unroll
    for (int bl = 0; bl < 2; ++bl)
#pragma unroll
      for (int q = 0; q < 4; ++q) mreg[mm][bl][q] = -__builtin_inff();

  const short* __restrict__ wbase = wr + (2 * mhat) * 512 + lane * 8;

// one d-tap: PD,TD literals -> acc[PD] and B3[2-TD] statically indexed
#define DTAP(PD, TD)                                                              \
  {                                                                               \
    const short8 a0v = *(const short8*)(wt + (PD + 2 * TD) * 25 * 2048);          \
    const short8 a1v = *(const short8*)(wt + (PD + 2 * TD) * 25 * 2048 + 512);    \
    _Pragma("unroll") for (int i = 0; i < 4; ++i) {                               \
      acc[PD][0][i] = __builtin_amdgcn_mfma_f32_16x16x32_bf16(                    \
          a0v, B3[2 - TD][i], acc[PD][0][i], 0, 0, 0);                            \
      acc[PD][1][i] = __builtin_amdgcn_mfma_f32_16x16x32_bf16(                    \
          a1v, B3[2 - TD][i], acc[PD][1][i], 0, 0, 0);                            \
    }                                                                             \
  }

#pragma unroll 1
  for (int php = 0; php < 4; ++php) {
    const int PH = php >> 1, PW = php & 1;
    f32x4 acc[2][2][4];  // [pd][mm][i]
#pragma unroll
    for (int pd = 0; pd < 2; ++pd)
#pragma unroll
      for (int mm = 0; mm < 2; ++mm)
#pragma unroll
        for (int i = 0; i < 4; ++i) acc[pd][mm][i] = (f32x4){0.f, 0.f, 0.f, 0.f};

#pragma unroll 1
    for (int th = 0; th <= 2 - PH; ++th) {
#pragma unroll 1
      for (int tw = 0; tw <= 2 - PW; ++tw) {
        const int hwoff8 = ((2 - th) * 5 + (2 - tw)) * 8;  // B common offset (shorts)
        short8 B3[3][4];  // [dd = 2-td][col]
#pragma unroll
        for (int dd = 0; dd < 3; ++dd)
#pragma unroll
          for (int i = 0; i < 4; ++i)
            B3[dd][i] = *(const short8*)&xs[baddr[i] + hwoff8 + dd * 200];

        const short* wt = wbase + ((PH + 2 * th) * 5 + (PW + 2 * tw)) * 2048;
        DTAP(0, 0)
        DTAP(0, 1)
        DTAP(0, 2)
        DTAP(1, 0)
        DTAP(1, 1)
      }
    }

    // merge both d-parities of this (PH,PW) pass into the pooled max
#pragma unroll
    for (int pd = 0; pd < 2; ++pd)
#pragma unroll
      for (int mm = 0; mm < 2; ++mm)
#pragma unroll
        for (int bl = 0; bl < 2; ++bl)
#pragma unroll
          for (int q = 0; q < 4; ++q)
            mreg[mm][bl][q] = fmaxf(mreg[mm][bl][q],
                                    fmaxf(acc[pd][mm][2 * bl][q], acc[pd][mm][2 * bl + 1][q]));
  }
#undef DTAP

  // ---- epilogue: max over cells (lane bits 0-3), +bias, sum over this half's couts ----
#pragma unroll
  for (int bl = 0; bl < 2; ++bl) {
    float s = 0.f;
#pragma unroll
    for (int mm = 0; mm < 2; ++mm)
#pragma unroll
      for (int q = 0; q < 4; ++q) {
        float v = mreg[mm][bl][q];
        v = fmaxf(v, __shfl_xor(v, 1));
        v = fmaxf(v, __shfl_xor(v, 2));
        v = fmaxf(v, __shfl_xor(v, 4));
        v = fmaxf(v, __shfl_xor(v, 8));
        s += v + bias[32 * mhat + 16 * mm + 4 * kb + q];
      }
    s += __shfl_xor(s, 16);  // sum across kb groups (8 distinct couts each)
    s += __shfl_xor(s, 32);
    if (lane == 0) red[mhat * 4 + 2 * bp + bl] = s;
  }
  __syncthreads();
  if (tid < 4) {  // tid = local batch; add the two cout halves
    out[(bg * 4 + tid) * 500 + r] = red[tid] + red[4 + tid];
  }
}

// ---------------- fallback (used only if ws too small) ----------------
__global__ __launch_bounds__(256) void fused_convt_pool(
    const float* __restrict__ x, const float* __restrict__ w,
    const float* __restrict__ bias, float* __restrict__ out) {
  __shared__ float xsf[CIN * 125];
  __shared__ float ws[COUT * 125];
  __shared__ float red[256];
  const int bi = blockIdx.x;
  const int b = bi / 500;
  const int r = bi % 500;
  const int od = r / 100, oh = (r / 10) % 10, ow = r % 10;
  const int tid = threadIdx.x;
  const int d0 = 3 * od - 1, h0 = 3 * oh - 1, w0 = 3 * ow - 1;
  for (int e = tid; e < CIN * 125; e += 256) {
    const int cin = e / 125, q = e % 125;
    const int id = q / 25, ih = (q / 5) % 5, iw = q % 5;
    const int gd = d0 + id, gh = h0 + ih, gw = w0 + iw;
    float v = 0.f;
    if (gd >= 0 && gh >= 0 && gw >= 0)
      v = x[(((b * CIN + cin) * 16 + gd) * 32 + gh) * 32 + gw];
    xsf[e] = v;
  }
  const int cout = tid >> 2;
  const int vs = tid & 3;
  int cellbase[7];
#pragma unroll
  for (int j = 0; j < 7; ++j) {
    int cell = vs + 4 * j;
    if (cell > 26) cell = 26;
    cellbase[j] = (cell / 9) * 25 + ((cell / 3) % 3) * 5 + cell % 3;
  }
  float acc[7][8];
#pragma unroll
  for (int j = 0; j < 7; ++j)
#pragma unroll
    for (int p = 0; p < 8; ++p) acc[j][p] = 0.f;
  for (int cin = 0; cin < CIN; ++cin) {
    __syncthreads();
    const float* wg = w + cin * (COUT * 125);
    for (int e = tid; e < COUT * 125; e += 256) ws[e] = wg[e];
    __syncthreads();
    const float* xc = xsf + cin * 125;
    const float* wc = ws + cout * 125;
#pragma unroll
    for (int pd = 0; pd < 2; ++pd)
#pragma unroll
      for (int ph = 0; ph < 2; ++ph)
#pragma unroll
        for (int pw = 0; pw < 2; ++pw) {
          const int P = pd * 4 + ph * 2 + pw;
          for (int td = 0; td <= 2 - pd; ++td)
            for (int th = 0; th <= 2 - ph; ++th)
              for (int tw = 0; tw <= 2 - pw; ++tw) {
                const float wv2 =
                    wc[(pd + 2 * td) * 25 + (ph + 2 * th) * 5 + (pw + 2 * tw)];
                const float* xp = xc + (2 - td) * 25 + (2 - th) * 5 + (2 - tw);
#pragma unroll
                for (int j = 0; j < 7; ++j)
                  acc[j][P] = fmaf(wv2, xp[cellbase[j]], acc[j][P]);
              }
        }
  }
  float m = acc[0][0];
#pragma unroll
  for (int j = 0; j < 7; ++j)
#pragma unroll
    for (int p = 0; p < 8; ++p) m = fmaxf(m, acc[j][p]);
  red[tid] = m;
  __syncthreads();
  if (tid < 64) {
    float cm = fmaxf(fmaxf(red[tid * 4 + 0], red[tid * 4 + 1]),
                     fmaxf(red[tid * 4 + 2], red[tid * 4 + 3]));
    cm += bias[tid];
    for (int off = 32; off > 0; off >>= 1) cm += __shfl_down(cm, off);
    if (tid == 0) out[bi] = cm;
  }
}

extern "C" void kernel_launch(void* const* d_in, const int* in_sizes, int n_in,
                              void* d_out, int out_size, void* d_ws, size_t ws_size,
                              hipStream_t stream) {
  const float* x = (const float*)d_in[0];
  const float* wgt = (const float*)d_in[1];
  const float* bias = (const float*)d_in[2];
  float* out = (float*)d_out;
  const size_t wr_bytes = 125 * 4 * 64 * 8 * sizeof(short);  // 512000
  if (ws_size >= wr_bytes) {
    short* wr = (short*)d_ws;
    reorder_w<<<125, 256, 0, stream>>>(wgt, wr);
    convt_mfma_r14<<<2000, 256, 0, stream>>>(x, wr, bias, out);
  } else {
    fused_convt_pool<<<8000, 256, 0, stream>>>(x, wgt, bias, out);
  }
}

// Round 15
// 131.304 us; speedup vs baseline: 1.4302x; 1.0626x over previous
//
#include <hip/hip_runtime.h>

// Fused ConvTranspose3d(32->64,K=5,S=2,P=2)+bias+MaxPool2+MaxPool3+channel-sum.
// Round 15: R14's d-axis B-register reuse (B-LDS 4GB->2.4GB; 27 distinct lane
// addresses, 3 d-frags held across 5 d-taps) + two reverts to proven settings:
//  (a) tw loop FREE to unroll (R6 precedent: ~3-group region schedules loads
//      ahead at ~88 VGPR, no spill; R14's unroll-1 on th AND tw left zero ILP ->
//      3 balanced pipes all ~45%, runtime 2.2x max-pipe)
//  (b) 512-thr/8-wave/8-batch blocks, 64KB LDS (R11's 16 waves/CU vs R14's 12)
//  - wave = 2 mtiles x (2 batches x 2 cell-tiles): A=2GB L1-bcast, MFMA-led floors
//  - acc[2][2][4] holds both d-parities per (PH,PW) pass; static DTAP bodies
//  - kb-major xs layout; 8-cin gather + ds_write_b128; XCD swizzle (1000%8==0)

typedef __attribute__((ext_vector_type(8))) short short8;
typedef __attribute__((ext_vector_type(4))) float f32x4;

#define CIN 32
#define COUT 64

static __device__ __forceinline__ short f2bf(float f) {
  unsigned u = __float_as_uint(f);
  return (short)((u + 0x7fffu + ((u >> 16) & 1u)) >> 16);  // RNE
}

// Wr[tap][mtile][lane][j] = bf16(W[cin=8*(lane>>4)+j][cout=16*mtile+(lane&15)][tap])
__global__ __launch_bounds__(256) void reorder_w(const float* __restrict__ w,
                                                 short* __restrict__ wr) {
  const int t = blockIdx.x * 256 + threadIdx.x;  // 0..31999
  const int l = t & 63, mt = (t >> 6) & 3, tap = t >> 8;
  const int cout = 16 * mt + (l & 15);
  const int kb = l >> 4;
  short8 v;
#pragma unroll
  for (int j = 0; j < 8; ++j)
    v[j] = f2bf(w[((8 * kb + j) * COUT + cout) * 125 + tap]);
  *(short8*)&wr[t * 8] = v;
}

// cell->column tables (pos = cd*25+ch*5+cw), residue-balanced mod 8.
#define E0 (0ULL | 1ULL<<6 | 2ULL<<12 | 27ULL<<18 | 52ULL<<24 | 5ULL<<30 | 6ULL<<36 | 7ULL<<42)
#define E1 (32ULL | 25ULL<<6 | 26ULL<<12 | 51ULL<<18 | 12ULL<<24 | 37ULL<<30 | 30ULL<<36 | 55ULL<<42)
#define O0 (56ULL | 57ULL<<6 | 50ULL<<12 | 11ULL<<18 | 36ULL<<24 | 61ULL<<30 | 62ULL<<36 | 31ULL<<42)
#define O1 (0ULL | 1ULL<<6 | 10ULL<<12 | 35ULL<<18 | 60ULL<<24 | 5ULL<<30 | 6ULL<<36 | 7ULL<<42)

__global__ __launch_bounds__(512) void convt_mfma_r15(
    const float* __restrict__ x, const short* __restrict__ wr,
    const float* __restrict__ bias, float* __restrict__ out) {
  __shared__ short xs[8 * 4 * 125 * 8];  // 64000 B: [bb][kb][pos] x 8 cins
  __shared__ float red[16];

  // XCD-bijective swizzle: 1000 blocks, 8 XCDs, 125 per XCD
  const int orig = blockIdx.x;
  const int bi = (orig & 7) * 125 + (orig >> 3);
  const int bg = bi / 500, r = bi % 500;
  const int od = r / 100, oh = (r / 10) % 10, ow = r % 10;
  const int tid = threadIdx.x;
  const int d0 = 3 * od - 1, h0 = 3 * oh - 1, w0 = 3 * ow - 1;
  const int xoff0 = d0 * 1024 + h0 * 32 + w0;

  // ---- stage x -> bf16 tile, 8-cin gather per thread, ds_write_b128 ----
  for (int e = tid; e < 8 * 4 * 128; e += 512) {  // 8 iters
    const int pos = e & 127;
    if (pos < 125) {
      const int kb = (e >> 7) & 3, bb = e >> 9;
      const int id = pos / 25, rem = pos - 25 * id;
      const int ih = rem / 5, iw = rem - 5 * ih;
      const bool ok = (d0 + id) >= 0 && (h0 + ih) >= 0 && (w0 + iw) >= 0;
      const float* xp =
          x + ((size_t)((bg * 8 + bb) * CIN + kb * 8) << 14) + xoff0 + id * 1024 + ih * 32 + iw;
      short8 v8;
#pragma unroll
      for (int j = 0; j < 8; ++j) v8[j] = f2bf(ok ? xp[j << 14] : 0.f);
      *(short8*)&xs[(bb * 500 + kb * 125 + pos) * 8] = v8;
    }
  }
  __syncthreads();

  const int lane = tid & 63, wv = tid >> 6;
  const int mhat = wv >> 2;  // cout half (0/1)
  const int bp = wv & 3;     // batch pair (0..3)
  const int kb = lane >> 4, c = lane & 15;

  const int pos_e = (int)((c < 8 ? (E0 >> (6 * c)) : (E1 >> (6 * (c - 8)))) & 63ULL);
  const int pos_o = (int)((c < 8 ? (O0 >> (6 * c)) : (O1 >> (6 * (c - 8)))) & 63ULL);

  int baddr[4];  // short-index base per B-frag, i = bl*2 + ct
#pragma unroll
  for (int i = 0; i < 4; ++i) {
    const int bb = 2 * bp + (i >> 1);
    baddr[i] = (bb * 500 + kb * 125 + ((i & 1) ? pos_o : pos_e)) * 8;
  }

  float mreg[2][2][4];  // [mm][bl][q]
#pragma unroll
  for (int mm = 0; mm < 2; ++mm)
#pragma unroll
    for (int bl = 0; bl < 2; ++bl)
#pragma unroll
      for (int q = 0; q < 4; ++q) mreg[mm][bl][q] = -__builtin_inff();

  const short* __restrict__ wbase = wr + (2 * mhat) * 512 + lane * 8;

// one d-tap: PD,TD literals -> acc[PD] and B3[2-TD] statically indexed
#define DTAP(PD, TD)                                                              \
  {                                                                               \
    const short8 a0v = *(const short8*)(wt + (PD + 2 * TD) * 25 * 2048);          \
    const short8 a1v = *(const short8*)(wt + (PD + 2 * TD) * 25 * 2048 + 512);    \
    _Pragma("unroll") for (int i = 0; i < 4; ++i) {                               \
      acc[PD][0][i] = __builtin_amdgcn_mfma_f32_16x16x32_bf16(                    \
          a0v, B3[2 - TD][i], acc[PD][0][i], 0, 0, 0);                            \
      acc[PD][1][i] = __builtin_amdgcn_mfma_f32_16x16x32_bf16(                    \
          a1v, B3[2 - TD][i], acc[PD][1][i], 0, 0, 0);                            \
    }                                                                             \
  }

#pragma unroll 1
  for (int php = 0; php < 4; ++php) {
    const int PH = php >> 1, PW = php & 1;
    f32x4 acc[2][2][4];  // [pd][mm][i]
#pragma unroll
    for (int pd = 0; pd < 2; ++pd)
#pragma unroll
      for (int mm = 0; mm < 2; ++mm)
#pragma unroll
        for (int i = 0; i < 4; ++i) acc[pd][mm][i] = (f32x4){0.f, 0.f, 0.f, 0.f};

#pragma unroll 1
    for (int th = 0; th <= 2 - PH; ++th) {
      // tw loop free: compiler schedules B3/A loads of group g+1 under group g's
      // MFMAs (<=3-group region, R6-proven scale)
      for (int tw = 0; tw <= 2 - PW; ++tw) {
        const int hwoff8 = ((2 - th) * 5 + (2 - tw)) * 8;  // B common offset (shorts)
        short8 B3[3][4];  // [dd = 2-td][col]
#pragma unroll
        for (int dd = 0; dd < 3; ++dd)
#pragma unroll
          for (int i = 0; i < 4; ++i)
            B3[dd][i] = *(const short8*)&xs[baddr[i] + hwoff8 + dd * 200];

        const short* wt = wbase + ((PH + 2 * th) * 5 + (PW + 2 * tw)) * 2048;
        DTAP(0, 0)
        DTAP(0, 1)
        DTAP(0, 2)
        DTAP(1, 0)
        DTAP(1, 1)
      }
    }

    // merge both d-parities of this (PH,PW) pass into the pooled max
#pragma unroll
    for (int pd = 0; pd < 2; ++pd)
#pragma unroll
      for (int mm = 0; mm < 2; ++mm)
#pragma unroll
        for (int bl = 0; bl < 2; ++bl)
#pragma unroll
          for (int q = 0; q < 4; ++q)
            mreg[mm][bl][q] = fmaxf(mreg[mm][bl][q],
                                    fmaxf(acc[pd][mm][2 * bl][q], acc[pd][mm][2 * bl + 1][q]));
  }
#undef DTAP

  // ---- epilogue: max over cells (lane bits 0-3), +bias, sum over this half's couts ----
#pragma unroll
  for (int bl = 0; bl < 2; ++bl) {
    float s = 0.f;
#pragma unroll
    for (int mm = 0; mm < 2; ++mm)
#pragma unroll
      for (int q = 0; q < 4; ++q) {
        float v = mreg[mm][bl][q];
        v = fmaxf(v, __shfl_xor(v, 1));
        v = fmaxf(v, __shfl_xor(v, 2));
        v = fmaxf(v, __shfl_xor(v, 4));
        v = fmaxf(v, __shfl_xor(v, 8));
        s += v + bias[32 * mhat + 16 * mm + 4 * kb + q];
      }
    s += __shfl_xor(s, 16);  // sum across kb groups (8 distinct couts each)
    s += __shfl_xor(s, 32);
    if (lane == 0) red[mhat * 8 + 2 * bp + bl] = s;
  }
  __syncthreads();
  if (tid < 8) {  // tid = local batch; add the two cout halves
    out[(bg * 8 + tid) * 500 + r] = red[tid] + red[8 + tid];
  }
}

// ---------------- fallback (used only if ws too small) ----------------
__global__ __launch_bounds__(256) void fused_convt_pool(
    const float* __restrict__ x, const float* __restrict__ w,
    const float* __restrict__ bias, float* __restrict__ out) {
  __shared__ float xsf[CIN * 125];
  __shared__ float ws[COUT * 125];
  __shared__ float red[256];
  const int bi = blockIdx.x;
  const int b = bi / 500;
  const int r = bi % 500;
  const int od = r / 100, oh = (r / 10) % 10, ow = r % 10;
  const int tid = threadIdx.x;
  const int d0 = 3 * od - 1, h0 = 3 * oh - 1, w0 = 3 * ow - 1;
  for (int e = tid; e < CIN * 125; e += 256) {
    const int cin = e / 125, q = e % 125;
    const int id = q / 25, ih = (q / 5) % 5, iw = q % 5;
    const int gd = d0 + id, gh = h0 + ih, gw = w0 + iw;
    float v = 0.f;
    if (gd >= 0 && gh >= 0 && gw >= 0)
      v = x[(((b * CIN + cin) * 16 + gd) * 32 + gh) * 32 + gw];
    xsf[e] = v;
  }
  const int cout = tid >> 2;
  const int vs = tid & 3;
  int cellbase[7];
#pragma unroll
  for (int j = 0; j < 7; ++j) {
    int cell = vs + 4 * j;
    if (cell > 26) cell = 26;
    cellbase[j] = (cell / 9) * 25 + ((cell / 3) % 3) * 5 + cell % 3;
  }
  float acc[7][8];
#pragma unroll
  for (int j = 0; j < 7; ++j)
#pragma unroll
    for (int p = 0; p < 8; ++p) acc[j][p] = 0.f;
  for (int cin = 0; cin < CIN; ++cin) {
    __syncthreads();
    const float* wg = w + cin * (COUT * 125);
    for (int e = tid; e < COUT * 125; e += 256) ws[e] = wg[e];
    __syncthreads();
    const float* xc = xsf + cin * 125;
    const float* wc = ws + cout * 125;
#pragma unroll
    for (int pd = 0; pd < 2; ++pd)
#pragma unroll
      for (int ph = 0; ph < 2; ++ph)
#pragma unroll
        for (int pw = 0; pw < 2; ++pw) {
          const int P = pd * 4 + ph * 2 + pw;
          for (int td = 0; td <= 2 - pd; ++td)
            for (int th = 0; th <= 2 - ph; ++th)
              for (int tw = 0; tw <= 2 - pw; ++tw) {
                const float wv2 =
                    wc[(pd + 2 * td) * 25 + (ph + 2 * th) * 5 + (pw + 2 * tw)];
                const float* xp = xc + (2 - td) * 25 + (2 - th) * 5 + (2 - tw);
#pragma unroll
                for (int j = 0; j < 7; ++j)
                  acc[j][P] = fmaf(wv2, xp[cellbase[j]], acc[j][P]);
              }
        }
  }
  float m = acc[0][0];
#pragma unroll
  for (int j = 0; j < 7; ++j)
#pragma unroll
    for (int p = 0; p < 8; ++p) m = fmaxf(m, acc[j][p]);
  red[tid] = m;
  __syncthreads();
  if (tid < 64) {
    float cm = fmaxf(fmaxf(red[tid * 4 + 0], red[tid * 4 + 1]),
                     fmaxf(red[tid * 4 + 2], red[tid * 4 + 3]));
    cm += bias[tid];
    for (int off = 32; off > 0; off >>= 1) cm += __shfl_down(cm, off);
    if (tid == 0) out[bi] = cm;
  }
}

extern "C" void kernel_launch(void* const* d_in, const int* in_sizes, int n_in,
                              void* d_out, int out_size, void* d_ws, size_t ws_size,
                              hipStream_t stream) {
  const float* x = (const float*)d_in[0];
  const float* wgt = (const float*)d_in[1];
  const float* bias = (const float*)d_in[2];
  float* out = (float*)d_out;
  const size_t wr_bytes = 125 * 4 * 64 * 8 * sizeof(short);  // 512000
  if (ws_size >= wr_bytes) {
    short* wr = (short*)d_ws;
    reorder_w<<<125, 256, 0, stream>>>(wgt, wr);
    convt_mfma_r15<<<1000, 512, 0, stream>>>(x, wr, bias, out);
  } else {
    fused_convt_pool<<<8000, 256, 0, stream>>>(x, wgt, bias, out);
  }
}